// Round 6
// baseline (251.735 us; speedup 1.0000x reference)
//
#include <hip/hip_runtime.h>
#include <cstddef>
#include <cstdint>

#define DIM   256
#define KCODE 8192
#define NTOK  16384
#define NCBG  16         // phase1 code groups of 512 (16 groups -> 4 blocks/CU)
#define HMARGIN 0.25f    // phase1 works in half-units (0.5*wn - dot)
#define UFLAG 0x40000000
#define BSTRIDE 264      // LDS B row stride in shorts (256 + 8 pad)

typedef __attribute__((ext_vector_type(8))) short short8;
typedef __attribute__((ext_vector_type(8))) unsigned short ushort8;
typedef __attribute__((ext_vector_type(4))) unsigned short ushort4v;
typedef __attribute__((ext_vector_type(4))) float floatx4;

__device__ __forceinline__ unsigned short f2bf(float f) {  // RNE float->bf16
  uint32_t u = __builtin_bit_cast(uint32_t, f);
  return (unsigned short)((u + 0x7fffu + ((u >> 16) & 1u)) >> 16);
}
__device__ __forceinline__ float bf2f(unsigned short h) {
  return __builtin_bit_cast(float, (uint32_t)h << 16);
}

// ---- kernel 1: bf16 split convert (x negated, w two-word) + w norms ----
__global__ __launch_bounds__(256) void prep_kernel(const float* __restrict__ x,
    const float* __restrict__ w, unsigned short* __restrict__ x0n,
    unsigned short* __restrict__ w0, unsigned short* __restrict__ w1,
    float* __restrict__ wn2, float* __restrict__ wnf, int* __restrict__ ucount) {
  if (blockIdx.x == 0 && threadIdx.x == 0) *ucount = 0;
  const int lane = threadIdx.x & 63, wv = threadIdx.x >> 6;
  const int l32 = lane & 31;
  const int row = blockIdx.x * 8 + wv * 2 + (lane >> 5);
  const bool is_x = row < NTOK;
  const float* src = is_x ? (x + (size_t)row * DIM) : (w + (size_t)(row - NTOK) * DIM);
  const float4 f0 = ((const float4*)src)[l32 * 2];
  const float4 f1 = ((const float4*)src)[l32 * 2 + 1];
  const float f[8] = {f0.x, f0.y, f0.z, f0.w, f1.x, f1.y, f1.z, f1.w};
  if (is_x) {  // store bf16(-x): MFMA then accumulates (norm - dot) directly
    ushort8 o;
#pragma unroll
    for (int i = 0; i < 8; ++i) o[i] = f2bf(-f[i]);
    *(ushort8*)(x0n + (size_t)row * DIM + l32 * 8) = o;
  } else {     // two-word split: w = w0 + w1 (+ ~2^-17 residual)
    ushort8 h, l;
#pragma unroll
    for (int i = 0; i < 8; ++i) {
      h[i] = f2bf(f[i]);
      l[i] = f2bf(f[i] - bf2f(h[i]));
    }
    *(ushort8*)(w0 + (size_t)(row - NTOK) * DIM + l32 * 8) = h;
    *(ushort8*)(w1 + (size_t)(row - NTOK) * DIM + l32 * 8) = l;
    float s = f[0]*f[0] + f[1]*f[1] + f[2]*f[2] + f[3]*f[3] +
              f[4]*f[4] + f[5]*f[5] + f[6]*f[6] + f[7]*f[7];
#pragma unroll
    for (int off = 1; off < 32; off <<= 1) s += __shfl_xor(s, off);
    if (l32 == 0) { wn2[row - NTOK] = 0.5f * s; wnf[row - NTOK] = s; }
  }
}

// ---- kernel 2: phase1 bf16 screen. A in VGPRs (64 tok/wave); B LDS-shared. ----
// block = 256 tok x 512 codes; grid 1024 = 4 blocks/CU (R5 was grid-pinned to
// 2/CU: 512 blocks / 256 CUs — the occupancy lever is GRID SHAPE). Per-sub
// work per wave unchanged vs R5 (64 MFMA, 16 ds_read_b128, 16KB stage); three
// phase-skewed co-resident blocks now fill each barrier drain (m114 overlap).
// R0 spill-free staging structure kept (deeper rings spill: R2-R4, 168MB).
__global__ __launch_bounds__(256) __attribute__((amdgpu_waves_per_eu(2, 8)))
void phase1_kernel(
    const unsigned short* __restrict__ x0n, const unsigned short* __restrict__ w0,
    const float* __restrict__ wn2,
    float* __restrict__ pv1, int* __restrict__ pc1, float* __restrict__ pv2) {
  __shared__ char smem[16896];  // B tile 32*264*2 B only
  unsigned short* Bs = (unsigned short*)smem;
  const int tid = threadIdx.x;
  const int tb = blockIdx.x >> 4;    // 0..63 (256 tokens)
  const int cbg = blockIdx.x & 15;   // 512-code group; low 3 bits = XCD (L2 slice reuse)
  const int lane = tid & 63, wv = tid >> 6;
  const int l15 = lane & 15, quad = lane >> 4;

  // resident A: wave wv owns 64 tokens; af[4][8] = 128 VGPRs
  short8 af[4][8];
#pragma unroll
  for (int mt = 0; mt < 4; ++mt) {
    const unsigned short* xr =
        x0n + (size_t)(tb * 256 + wv * 64 + mt * 16 + l15) * DIM + quad * 8;
#pragma unroll
    for (int kc = 0; kc < 8; ++kc) af[mt][kc] = *(const short8*)(xr + kc * 32);
  }

  float bv1[16], bv2[16];
  int bc1[16];
#pragma unroll
  for (int i = 0; i < 16; ++i) { bv1[i] = -3.4e38f; bv2[i] = -3.4e38f; bc1[i] = 0; }

  // staging: k-th instr: row = (tid>>5) + k*8 (0..31 over k=0..3), col = (tid&31)*16B
  const int s_row = tid >> 5;
  const int s_col = (tid & 31) * 8;  // shorts
  const unsigned short* gsrc = w0 + (size_t)(cbg * 512 + s_row) * DIM + s_col;
  unsigned short* ldst = Bs + s_row * BSTRIDE + s_col;

  int4 st[4];
#pragma unroll
  for (int k = 0; k < 4; ++k) st[k] = *(const int4*)(gsrc + k * 2048);  // sub 0
  const float* wnp = wn2 + cbg * 512 + l15;
  float nw0 = wnp[0], nw1 = wnp[16];
  int code0 = cbg * 512 + l15;

#pragma unroll 1
  for (int sub = 0; sub < 16; ++sub) {
    __syncthreads();   // previous sub's ds_reads complete
#pragma unroll
    for (int k = 0; k < 4; ++k) *(int4*)(ldst + k * 8 * BSTRIDE) = st[k];
    __syncthreads();   // tile visible
    if (sub < 15) {    // prefetch sub+1 (32 rows = 8192 shorts ahead)
      const unsigned short* gn = gsrc + (size_t)(sub + 1) * 8192;
#pragma unroll
      for (int k = 0; k < 4; ++k) st[k] = *(const int4*)(gn + k * 2048);
    }
    const float cw0 = nw0, cw1 = nw1;
    wnp += 32;
    if (sub < 15) { nw0 = wnp[0]; nw1 = wnp[16]; }
    floatx4 acc[4][2];
#pragma unroll
    for (int mt = 0; mt < 4; ++mt) {
      acc[mt][0] = (floatx4){cw0, cw0, cw0, cw0};
      acc[mt][1] = (floatx4){cw1, cw1, cw1, cw1};
    }
#pragma unroll
    for (int kc = 0; kc < 8; ++kc) {
      const short8 b0 = *(const short8*)(Bs + l15 * BSTRIDE + kc * 32 + quad * 8);
      const short8 b1 = *(const short8*)(Bs + (16 + l15) * BSTRIDE + kc * 32 + quad * 8);
#pragma unroll
      for (int mt = 0; mt < 4; ++mt) {
        acc[mt][0] = __builtin_amdgcn_mfma_f32_16x16x32_bf16(af[mt][kc], b0, acc[mt][0], 0, 0, 0);
        acc[mt][1] = __builtin_amdgcn_mfma_f32_16x16x32_bf16(af[mt][kc], b1, acc[mt][1], 0, 0, 0);
      }
    }
    // acc = wn/2 - dot. Pair-merge 2 candidates/cell into running top-2.
#pragma unroll
    for (int mt = 0; mt < 4; ++mt) {
#pragma unroll
      for (int reg = 0; reg < 4; ++reg) {
        const int cell = mt * 4 + reg;
        const float c0 = acc[mt][0][reg], c1 = acc[mt][1][reg];
        const float hi = fmaxf(c0, c1), lo = fminf(c0, c1);
        const int ch = (c1 > c0) ? (code0 + 16) : code0;  // tie -> lower code
        const float t = fminf(bv1[cell], hi);
        bc1[cell] = (hi > bv1[cell]) ? ch : bc1[cell];    // tie -> earlier (lower)
        bv1[cell] = fmaxf(bv1[cell], hi);
        bv2[cell] = fmaxf(fmaxf(bv2[cell], t), lo);       // v_max3_f32
      }
    }
    code0 += 32;
  }

  // epilogue: the 16 per-token candidates live in lanes quad*16+l15 of THIS
  // wave -> 16-lane xor-butterfly top-2 merge, no LDS, no barriers.
  // Ties: V2 ends == V1 -> gap 0 -> rescore; lane 0 keeps lowest tying code.
#pragma unroll
  for (int mt = 0; mt < 4; ++mt)
#pragma unroll
    for (int reg = 0; reg < 4; ++reg) {
      const int cell = mt * 4 + reg;
      float V1 = bv1[cell], V2 = bv2[cell];
      int C1 = bc1[cell];
#pragma unroll
      for (int off = 1; off < 16; off <<= 1) {
        const float ov1 = __shfl_xor(V1, off);
        const float ov2 = __shfl_xor(V2, off);
        const int   oc1 = __shfl_xor(C1, off);
        const bool take = ov1 > V1;
        V2 = fmaxf(fminf(V1, ov1), take ? ov2 : V2);
        V1 = take ? ov1 : V1;
        C1 = take ? oc1 : C1;
      }
      if (l15 == 0) {
        const int tok = wv * 64 + mt * 16 + quad * 4 + reg;  // C/D: row=quad*4+reg
        const size_t o = (size_t)cbg * NTOK + tb * 256 + tok;
        pv1[o] = V1; pc1[o] = C1; pv2[o] = V2;
      }
    }
}

// ---- kernel 3: merge 16 code-group partials; flagged final_idx + uncertain list ----
__global__ __launch_bounds__(256) void reduce_kernel(
    const float* __restrict__ pv1, const int* __restrict__ pc1,
    const float* __restrict__ pv2, int* __restrict__ final_idx,
    int* __restrict__ ucount, int* __restrict__ ulist) {
  const int n = blockIdx.x * 256 + threadIdx.x;
  float V1 = -3.4e38f, V2 = -3.4e38f;
  int C1 = 0;
#pragma unroll
  for (int cb = 0; cb < NCBG; ++cb) {
    const size_t o = (size_t)cb * NTOK + n;
    const float v1 = pv1[o], v2 = pv2[o];
    const int c1 = pc1[o];
    if (v1 > V1) { V2 = fmaxf(V1, v2); V1 = v1; C1 = c1; }
    else V2 = fmaxf(V2, v1);
  }
  if (V1 - V2 < HMARGIN) {
    const int p = atomicAdd(ucount, 1);
    ulist[p] = n;
    final_idx[n] = UFLAG | p;   // gather resolves via p2 slot p
  } else {
    final_idx[n] = C1;
  }
}

// ---- kernel 4: gather uncertain tokens into compact two-word bf16 rows ----
__global__ __launch_bounds__(256) void xgather_kernel(const float* __restrict__ x,
    const unsigned short* __restrict__ x0n, const int* __restrict__ ucount,
    const int* __restrict__ ulist, unsigned short* __restrict__ xgh,
    unsigned short* __restrict__ xgl) {
  const int uc = *ucount;
  const int ucp = (uc + 63) & ~63;
  const int wgid = blockIdx.x * 4 + (threadIdx.x >> 6);
  const int lane = threadIdx.x & 63;
  for (int s = wgid; s < ucp; s += 1024) {
    ushort4v h = (ushort4v){0, 0, 0, 0}, l = (ushort4v){0, 0, 0, 0};
    if (s < uc) {
      const int tok = ulist[s];
      h = ((const ushort4v*)(x0n + (size_t)tok * DIM))[lane];
      const float4 f = ((const float4*)(x + (size_t)tok * DIM))[lane];
      l[0] = f2bf(-f.x - bf2f(h[0]));
      l[1] = f2bf(-f.y - bf2f(h[1]));
      l[2] = f2bf(-f.z - bf2f(h[2]));
      l[3] = f2bf(-f.w - bf2f(h[3]));
    }
    ((ushort4v*)(xgh + (size_t)s * DIM))[lane] = h;
    ((ushort4v*)(xgl + (size_t)s * DIM))[lane] = l;
  }
}

// ---- kernel 5: exact-ish rescore via 2-word bf16 split MFMA (4 products) ----
// block = 64 slots x 256-code slice; grid 2048 = 64 g-slots x 32 slices
__global__ __launch_bounds__(256) __attribute__((amdgpu_waves_per_eu(2, 4)))
void rescore_kernel(
    const unsigned short* __restrict__ xgh, const unsigned short* __restrict__ xgl,
    const unsigned short* __restrict__ w0, const unsigned short* __restrict__ w1,
    const float* __restrict__ wnf, const int* __restrict__ ucount,
    float* __restrict__ p2v, int* __restrict__ p2c) {
  const int uc = *ucount;
  if (uc == 0) return;
  const int ucp = (uc + 63) & ~63;
  const int sl = blockIdx.x & 31, g0 = blockIdx.x >> 5;
  __shared__ float red2[4096];  // 16 KB: rv[2048] rc[2048]
  const int tid = threadIdx.x;
  const int lane = tid & 63, wv = tid >> 6;
  const int wm = wv & 1, wnb = wv >> 1;
  const int l15 = lane & 15, quad = lane >> 4;

  for (int g = g0; g * 64 < ucp; g += 64) {
    short8 ah[2][8], al[2][8];  // 128 VGPRs
#pragma unroll
    for (int mt = 0; mt < 2; ++mt) {
      const size_t rb = (size_t)(g * 64 + wm * 32 + mt * 16 + l15) * DIM + quad * 8;
#pragma unroll
      for (int kc = 0; kc < 8; ++kc) {
        ah[mt][kc] = *(const short8*)(xgh + rb + kc * 32);
        al[mt][kc] = *(const short8*)(xgl + rb + kc * 32);
      }
    }
    float bv[8];
    int bc[8];
#pragma unroll
    for (int i = 0; i < 8; ++i) { bv[i] = -3.4e38f; bc[i] = 0; }

    const unsigned short* wph = w0 + (size_t)(sl * 256 + wnb * 32 + l15) * DIM + quad * 8;
    const unsigned short* wpl = w1 + (size_t)(sl * 256 + wnb * 32 + l15) * DIM + quad * 8;
    const float* wnp = wnf + sl * 256 + wnb * 32 + l15;
    int code0 = sl * 256 + wnb * 32 + l15;

#pragma unroll 1
    for (int sub = 0; sub < 4; ++sub) {
      floatx4 acc[2][2];
#pragma unroll
      for (int mt = 0; mt < 2; ++mt)
#pragma unroll
        for (int nt = 0; nt < 2; ++nt) acc[mt][nt] = (floatx4){0.f, 0.f, 0.f, 0.f};
#pragma unroll
      for (int kc = 0; kc < 8; ++kc) {
        const short8 bh0 = *(const short8*)(wph + kc * 32);
        const short8 bh1 = *(const short8*)(wph + 16 * DIM + kc * 32);
        const short8 bl0 = *(const short8*)(wpl + kc * 32);
        const short8 bl1 = *(const short8*)(wpl + 16 * DIM + kc * 32);
#pragma unroll
        for (int mt = 0; mt < 2; ++mt) {
          acc[mt][0] = __builtin_amdgcn_mfma_f32_16x16x32_bf16(al[mt][kc], bl0, acc[mt][0], 0, 0, 0);
          acc[mt][0] = __builtin_amdgcn_mfma_f32_16x16x32_bf16(ah[mt][kc], bl0, acc[mt][0], 0, 0, 0);
          acc[mt][0] = __builtin_amdgcn_mfma_f32_16x16x32_bf16(al[mt][kc], bh0, acc[mt][0], 0, 0, 0);
          acc[mt][0] = __builtin_amdgcn_mfma_f32_16x16x32_bf16(ah[mt][kc], bh0, acc[mt][0], 0, 0, 0);
          acc[mt][1] = __builtin_amdgcn_mfma_f32_16x16x32_bf16(al[mt][kc], bl1, acc[mt][1], 0, 0, 0);
          acc[mt][1] = __builtin_amdgcn_mfma_f32_16x16x32_bf16(ah[mt][kc], bl1, acc[mt][1], 0, 0, 0);
          acc[mt][1] = __builtin_amdgcn_mfma_f32_16x16x32_bf16(al[mt][kc], bh1, acc[mt][1], 0, 0, 0);
          acc[mt][1] = __builtin_amdgcn_mfma_f32_16x16x32_bf16(ah[mt][kc], bh1, acc[mt][1], 0, 0, 0);
        }
      }
      const float wn0 = wnp[0], wn1 = wnp[16];
      // acc = -(x.w); dist = wn + 2*acc
#pragma unroll
      for (int mt = 0; mt < 2; ++mt) {
#pragma unroll
        for (int reg = 0; reg < 4; ++reg) {
          const int cell = mt * 4 + reg;
          const float d0 = fmaf(2.0f, acc[mt][0][reg], wn0);
          const float d1 = fmaf(2.0f, acc[mt][1][reg], wn1);
          const float hi = fmaxf(d0, d1);
          const int ch = (d1 > d0) ? (code0 + 16) : code0;  // tie -> lower code
          bc[cell] = (hi > bv[cell]) ? ch : bc[cell];
          bv[cell] = fmaxf(bv[cell], hi);
        }
      }
      wph += (size_t)64 * DIM;
      wpl += (size_t)64 * DIM;
      wnp += 64;
      code0 += 64;
    }

    // epilogue: cross-column reduce for this g-group
    float* rv = red2;
    int* rc = (int*)(red2 + 2048);
    __syncthreads();  // protect red2 reuse across g iterations
    const int cg = wnb * 16 + l15;
#pragma unroll
    for (int mt = 0; mt < 2; ++mt)
#pragma unroll
      for (int reg = 0; reg < 4; ++reg) {
        const int tok = wm * 32 + mt * 16 + quad * 4 + reg;
        rv[tok * 32 + cg] = bv[mt * 4 + reg];
        rc[tok * 32 + cg] = bc[mt * 4 + reg];
      }
    __syncthreads();
    if (tid < 64) {
      const int s = g * 64 + tid;
      if (s < uc) {
        float V = rv[tid * 32];
        int C = rc[tid * 32];
#pragma unroll 4
        for (int j = 1; j < 32; ++j) {
          const float v = rv[tid * 32 + j];
          const int c = rc[tid * 32 + j];
          if (v > V || (v == V && c < C)) { V = v; C = c; }
        }
        p2v[(size_t)sl * NTOK + s] = V;
        p2c[(size_t)sl * NTOK + s] = C;
      }
    }
  }
}

// ---- kernel 6: fused slice-merge + gather ----
__global__ __launch_bounds__(256) void gather_kernel(const float* __restrict__ w,
    const int* __restrict__ final_idx, const float* __restrict__ p2v,
    const int* __restrict__ p2c, float* __restrict__ out) {
  const int lane = threadIdx.x & 63;
  const int n = blockIdx.x * 4 + (threadIdx.x >> 6);
  int f = final_idx[n];
  if (f & UFLAG) {
    const int s = f & 0x3FFF;
    const int sl = lane & 31;
    float v = p2v[(size_t)sl * NTOK + s];
    int c = p2c[(size_t)sl * NTOK + s];
#pragma unroll
    for (int off = 1; off < 32; off <<= 1) {
      const float ov = __shfl_xor(v, off);
      const int oc = __shfl_xor(c, off);
      if (ov > v || (ov == v && oc < c)) { v = ov; c = oc; }
    }
    f = c;  // uniform across each 32-lane half (both halves identical)
  }
  ((float4*)(out + (size_t)n * DIM))[lane] = ((const float4*)(w + (size_t)f * DIM))[lane];
}

extern "C" void kernel_launch(void* const* d_in, const int* in_sizes, int n_in,
                              void* d_out, int out_size, void* d_ws, size_t ws_size,
                              hipStream_t stream) {
  const float* x = (const float*)d_in[0];
  const float* w = (const float*)d_in[1];
  float* out = (float*)d_out;

  char* ws = (char*)d_ws;   // ~41.1 MB used
  unsigned short* x0n = (unsigned short*)(ws);             // 8388608
  unsigned short* w0 = (unsigned short*)(ws + 8388608);    // 4194304
  unsigned short* w1 = (unsigned short*)(ws + 12582912);   // 4194304
  float* wn2 = (float*)(ws + 16777216);                    // 32768
  float* wnf = (float*)(ws + 16809984);                    // 32768
  float* pv1 = (float*)(ws + 16842752);                    // 1048576 (16 groups)
  int*   pc1 = (int*)  (ws + 17891328);                    // 1048576
  float* pv2 = (float*)(ws + 18939904);                    // 1048576
  int* final_idx = (int*)(ws + 19988480);                  // 65536
  int* ucount = (int*)(ws + 20054016);                     // 256
  int* ulist  = (int*)(ws + 20054272);                     // 65536
  unsigned short* xgh = (unsigned short*)(ws + 20119808);  // 8388608
  unsigned short* xgl = (unsigned short*)(ws + 28508416);  // 8388608
  float* p2v = (float*)(ws + 36897024);                    // 2097152
  int*   p2c = (int*)  (ws + 38994176);                    // 2097152

  prep_kernel<<<3072, 256, 0, stream>>>(x, w, x0n, w0, w1, wn2, wnf, ucount);
  phase1_kernel<<<64 * NCBG, 256, 0, stream>>>(x0n, w0, wn2, pv1, pc1, pv2);
  reduce_kernel<<<NTOK / 256, 256, 0, stream>>>(pv1, pc1, pv2, final_idx, ucount, ulist);
  xgather_kernel<<<256, 256, 0, stream>>>(x, x0n, ucount, ulist, xgh, xgl);
  rescore_kernel<<<64 * 32, 256, 0, stream>>>(xgh, xgl, w0, w1, wnf, ucount, p2v, p2c);
  gather_kernel<<<NTOK / 4, 256, 0, stream>>>(w, final_idx, p2v, p2c, out);
}

// Round 7
// 194.311 us; speedup vs baseline: 1.2955x; 1.2955x over previous
//
#include <hip/hip_runtime.h>
#include <cstddef>
#include <cstdint>

#define DIM   256
#define KCODE 8192
#define NTOK  16384
#define NCBG  8          // phase1 code groups of 1024
#define HMARGIN 0.25f    // phase1 works in half-units (0.5*wn - dot)
#define UFLAG 0x40000000

typedef __attribute__((ext_vector_type(8))) short short8;
typedef __attribute__((ext_vector_type(8))) unsigned short ushort8;
typedef __attribute__((ext_vector_type(4))) unsigned short ushort4v;
typedef __attribute__((ext_vector_type(4))) float floatx4;

__device__ __forceinline__ unsigned short f2bf(float f) {  // RNE float->bf16
  uint32_t u = __builtin_bit_cast(uint32_t, f);
  return (unsigned short)((u + 0x7fffu + ((u >> 16) & 1u)) >> 16);
}
__device__ __forceinline__ float bf2f(unsigned short h) {
  return __builtin_bit_cast(float, (uint32_t)h << 16);
}

typedef const __attribute__((address_space(1))) unsigned int guint_t;
typedef __attribute__((address_space(3))) unsigned int luint_t;
__device__ __forceinline__ void gload_lds16(const void* g, void* l) {
  __builtin_amdgcn_global_load_lds((guint_t*)g, (luint_t*)l, 16, 0, 0);
}

// ---- TILED w0/w1 global layout (verified bit-exact in R3/R4) ----
// tile t = 32 codebook rows (16 KB). Region (kc,h) = 1024 B at (kc*2+h)*1024.
// Slot s = quad*16 + (l15^kc) (16 B) holds chunk (row h*16+l15, 16B-col kc*4+quad).
// A wave DMA of one region (base + lane*16) is contiguous 1024 B in global AND
// lands as the conflict-free k-major LDS image (reads: lane*16 ^ kc<<4).

// ---- kernel 1: bf16 split convert (x negated, w two-word TILED) + w norms ----
__global__ __launch_bounds__(256) void prep_kernel(const float* __restrict__ x,
    const float* __restrict__ w, unsigned short* __restrict__ x0n,
    unsigned short* __restrict__ w0, unsigned short* __restrict__ w1,
    float* __restrict__ wn2, float* __restrict__ wnf, int* __restrict__ ucount) {
  if (blockIdx.x == 0 && threadIdx.x == 0) *ucount = 0;
  const int lane = threadIdx.x & 63, wv = threadIdx.x >> 6;
  const int l32 = lane & 31;
  const int row = blockIdx.x * 8 + wv * 2 + (lane >> 5);
  const bool is_x = row < NTOK;
  const float* src = is_x ? (x + (size_t)row * DIM) : (w + (size_t)(row - NTOK) * DIM);
  const float4 f0 = ((const float4*)src)[l32 * 2];
  const float4 f1 = ((const float4*)src)[l32 * 2 + 1];
  const float f[8] = {f0.x, f0.y, f0.z, f0.w, f1.x, f1.y, f1.z, f1.w};
  if (is_x) {  // store bf16(-x): MFMA then accumulates (norm - dot) directly
    ushort8 o;
#pragma unroll
    for (int i = 0; i < 8; ++i) o[i] = f2bf(-f[i]);
    *(ushort8*)(x0n + (size_t)row * DIM + l32 * 8) = o;
  } else {     // two-word split: w = w0 + w1 (+ ~2^-17 residual), TILED store
    ushort8 h8, l8;
#pragma unroll
    for (int i = 0; i < 8; ++i) {
      h8[i] = f2bf(f[i]);
      l8[i] = f2bf(f[i] - bf2f(h8[i]));
    }
    const int wr = row - NTOK;
    const int kc = l32 >> 2, quad = l32 & 3;
    const size_t off = (size_t)(wr >> 5) * 8192                      // tile (shorts)
                     + (size_t)(kc * 2 + ((wr >> 4) & 1)) * 512      // region
                     + (size_t)(quad * 16 + ((wr & 15) ^ kc)) * 8;   // slot
    *(ushort8*)(w0 + off) = h8;
    *(ushort8*)(w1 + off) = l8;
    float s = f[0]*f[0] + f[1]*f[1] + f[2]*f[2] + f[3]*f[3] +
              f[4]*f[4] + f[5]*f[5] + f[6]*f[6] + f[7]*f[7];
#pragma unroll
    for (int off2 = 1; off2 < 32; off2 <<= 1) s += __shfl_xor(s, off2);
    if (l32 == 0) { wn2[wr] = 0.5f * s; wnf[wr] = s; }
  }
}

// ---- kernel 2: phase1 bf16 screen. 32 tok/wave (half register state). ----
// block = 128 tok x 1024 codes; grid 1024. Staging: global_load_lds DMA of
// pre-tiled w0 (zero staging registers, m97 structure), 2x16KB double buffer,
// ONE __syncthreads per sub: DMA tile s+1 issued right after the barrier,
// compute tile s (~2500cyc hides DMA), barrier drains vmcnt -> tile ready.
// No inline asm / counted vmcnt (R2-R4 spill trigger). Reads conflict-free
// (lane*16 ^ kc<<4; verified 2e5 conflicts in R3). waves_per_eu(3,8): ~135-reg
// footprint -> >=3 waves/SIMD (R0-R6 were pinned at 2 by the 64-tok af array).
__global__ __launch_bounds__(256) __attribute__((amdgpu_waves_per_eu(3, 8)))
void phase1_kernel(
    const unsigned short* __restrict__ x0n, const unsigned short* __restrict__ w0,
    const float* __restrict__ wn2,
    float* __restrict__ pv1, int* __restrict__ pc1, float* __restrict__ pv2) {
  __shared__ char smem[32768];  // 2 x 16KB B-tile double buffer
  const int tid = threadIdx.x;
  const int tb = blockIdx.x >> 3;    // 0..127 (128 tokens)
  const int cbg = blockIdx.x & 7;    // blockIdx%8 = XCD -> 512KB w0 slice per XCD L2
  const int lane = tid & 63, wv = tid >> 6;
  const int l15 = lane & 15, quad = lane >> 4;
  const int lane16 = lane << 4;

  // DMA sources: wave wv stages regions rho = wv*4+j; contiguous 1024B each.
  const char* wb = (const char*)w0 + (size_t)cbg * 32 * 16384;  // 512KB slice
  const char* g0 = wb + (wv * 4 + 0) * 1024 + lane16;
  const char* g1 = wb + (wv * 4 + 1) * 1024 + lane16;
  const char* g2 = wb + (wv * 4 + 2) * 1024 + lane16;
  const char* g3 = wb + (wv * 4 + 3) * 1024 + lane16;

#define P1_DMA(BUFOFF) { \
    gload_lds16(g0, smem + (BUFOFF) + (wv * 4 + 0) * 1024); \
    gload_lds16(g1, smem + (BUFOFF) + (wv * 4 + 1) * 1024); \
    gload_lds16(g2, smem + (BUFOFF) + (wv * 4 + 2) * 1024); \
    gload_lds16(g3, smem + (BUFOFF) + (wv * 4 + 3) * 1024); \
    g0 += 16384; g1 += 16384; g2 += 16384; g3 += 16384; }

  P1_DMA(0)   // tile 0 -> buf0; lands while we load A below

  // resident A: wave wv owns 32 tokens; af[2][8] = 64 VGPRs
  short8 af[2][8];
#pragma unroll
  for (int mt = 0; mt < 2; ++mt) {
    const unsigned short* xr =
        x0n + (size_t)(tb * 128 + wv * 32 + mt * 16 + l15) * DIM + quad * 8;
#pragma unroll
    for (int kc = 0; kc < 8; ++kc) af[mt][kc] = *(const short8*)(xr + kc * 32);
  }

  float bv1[8], bv2[8];
  int bc1[8];
#pragma unroll
  for (int i = 0; i < 8; ++i) { bv1[i] = -3.4e38f; bv2[i] = -3.4e38f; bc1[i] = 0; }

  const float* wnp = wn2 + cbg * 1024 + l15;
  float nw0 = wnp[0], nw1 = wnp[16];
  int code0 = cbg * 1024 + l15;

#define P1_COMPUTE(BUF, LOADN) { \
    const float cw0 = nw0, cw1 = nw1; \
    wnp += 32; \
    if (LOADN) { nw0 = wnp[0]; nw1 = wnp[16]; } \
    floatx4 acc[2][2]; \
    _Pragma("unroll") \
    for (int mt = 0; mt < 2; ++mt) { \
      acc[mt][0] = (floatx4){cw0, cw0, cw0, cw0}; \
      acc[mt][1] = (floatx4){cw1, cw1, cw1, cw1}; \
    } \
    _Pragma("unroll") \
    for (int kc = 0; kc < 8; ++kc) { \
      const int ra = lane16 ^ (kc << 4); \
      const short8 b0 = *(const short8*)(smem + (BUF) + kc * 2048 + ra); \
      const short8 b1 = *(const short8*)(smem + (BUF) + kc * 2048 + 1024 + ra); \
      _Pragma("unroll") \
      for (int mt = 0; mt < 2; ++mt) { \
        acc[mt][0] = __builtin_amdgcn_mfma_f32_16x16x32_bf16(af[mt][kc], b0, acc[mt][0], 0, 0, 0); \
        acc[mt][1] = __builtin_amdgcn_mfma_f32_16x16x32_bf16(af[mt][kc], b1, acc[mt][1], 0, 0, 0); \
      } \
    } \
    _Pragma("unroll") \
    for (int mt = 0; mt < 2; ++mt) { \
      _Pragma("unroll") \
      for (int reg = 0; reg < 4; ++reg) { \
        const int cell = mt * 4 + reg; \
        const float c0 = acc[mt][0][reg], c1 = acc[mt][1][reg]; \
        const float hi = fmaxf(c0, c1), lo = fminf(c0, c1); \
        const int ch = (c1 > c0) ? (code0 + 16) : code0;  /* tie -> lower code */ \
        const float t = fminf(bv1[cell], hi); \
        bc1[cell] = (hi > bv1[cell]) ? ch : bc1[cell];    /* tie -> earlier */ \
        bv1[cell] = fmaxf(bv1[cell], hi); \
        bv2[cell] = fmaxf(fmaxf(bv2[cell], t), lo);       /* v_max3_f32 */ \
      } \
    } \
    code0 += 32; }

  __syncthreads();   // tile 0 landed (compiler drains vmcnt at barrier)

  // Per sub s: issue DMA tile s+1 into the other buffer (its last readers
  // finished before the barrier we just passed), compute tile s, barrier
  // (drains the DMA -> tile s+1 ready; all waves done reading buf s).
#pragma unroll 1
  for (int s2 = 0; s2 < 16; ++s2) {
    P1_DMA(16384)                          // tile 2*s2+1 -> buf1
    P1_COMPUTE(0, 1)                       // sub 2*s2
    __syncthreads();
    if (s2 < 15) P1_DMA(0)                 // tile 2*s2+2 -> buf0
    P1_COMPUTE(16384, (s2 < 15))           // sub 2*s2+1
    __syncthreads();
  }
#undef P1_DMA
#undef P1_COMPUTE

  // epilogue: the 16 per-token candidates live in lanes quad*16+l15 of THIS
  // wave -> 16-lane xor-butterfly top-2 merge, no LDS, no barriers.
  // Ties: V2 ends == V1 -> gap 0 -> rescore; lane 0 keeps lowest tying code.
#pragma unroll
  for (int mt = 0; mt < 2; ++mt)
#pragma unroll
    for (int reg = 0; reg < 4; ++reg) {
      const int cell = mt * 4 + reg;
      float V1 = bv1[cell], V2 = bv2[cell];
      int C1 = bc1[cell];
#pragma unroll
      for (int off = 1; off < 16; off <<= 1) {
        const float ov1 = __shfl_xor(V1, off);
        const float ov2 = __shfl_xor(V2, off);
        const int   oc1 = __shfl_xor(C1, off);
        const bool take = ov1 > V1;
        V2 = fmaxf(fminf(V1, ov1), take ? ov2 : V2);
        V1 = take ? ov1 : V1;
        C1 = take ? oc1 : C1;
      }
      if (l15 == 0) {
        const int tok = wv * 32 + mt * 16 + quad * 4 + reg;  // C/D: row=quad*4+reg
        const size_t o = (size_t)cbg * NTOK + tb * 128 + tok;
        pv1[o] = V1; pc1[o] = C1; pv2[o] = V2;
      }
    }
}

// ---- kernel 3: merge 8 code-group partials; flagged final_idx + uncertain list ----
__global__ __launch_bounds__(256) void reduce_kernel(
    const float* __restrict__ pv1, const int* __restrict__ pc1,
    const float* __restrict__ pv2, int* __restrict__ final_idx,
    int* __restrict__ ucount, int* __restrict__ ulist) {
  const int n = blockIdx.x * 256 + threadIdx.x;
  float V1 = -3.4e38f, V2 = -3.4e38f;
  int C1 = 0;
#pragma unroll
  for (int cb = 0; cb < NCBG; ++cb) {
    const size_t o = (size_t)cb * NTOK + n;
    const float v1 = pv1[o], v2 = pv2[o];
    const int c1 = pc1[o];
    if (v1 > V1) { V2 = fmaxf(V1, v2); V1 = v1; C1 = c1; }
    else V2 = fmaxf(V2, v1);
  }
  if (V1 - V2 < HMARGIN) {
    const int p = atomicAdd(ucount, 1);
    ulist[p] = n;
    final_idx[n] = UFLAG | p;   // gather resolves via p2 slot p
  } else {
    final_idx[n] = C1;
  }
}

// ---- kernel 4: gather uncertain tokens into compact two-word bf16 rows ----
__global__ __launch_bounds__(256) void xgather_kernel(const float* __restrict__ x,
    const unsigned short* __restrict__ x0n, const int* __restrict__ ucount,
    const int* __restrict__ ulist, unsigned short* __restrict__ xgh,
    unsigned short* __restrict__ xgl) {
  const int uc = *ucount;
  const int ucp = (uc + 63) & ~63;
  const int wgid = blockIdx.x * 4 + (threadIdx.x >> 6);
  const int lane = threadIdx.x & 63;
  for (int s = wgid; s < ucp; s += 1024) {
    ushort4v h = (ushort4v){0, 0, 0, 0}, l = (ushort4v){0, 0, 0, 0};
    if (s < uc) {
      const int tok = ulist[s];
      h = ((const ushort4v*)(x0n + (size_t)tok * DIM))[lane];
      const float4 f = ((const float4*)(x + (size_t)tok * DIM))[lane];
      l[0] = f2bf(-f.x - bf2f(h[0]));
      l[1] = f2bf(-f.y - bf2f(h[1]));
      l[2] = f2bf(-f.z - bf2f(h[2]));
      l[3] = f2bf(-f.w - bf2f(h[3]));
    }
    ((ushort4v*)(xgh + (size_t)s * DIM))[lane] = h;
    ((ushort4v*)(xgl + (size_t)s * DIM))[lane] = l;
  }
}

// ---- kernel 5: exact-ish rescore via 2-word bf16 split MFMA (4 products) ----
// block = 64 slots x 256-code slice; grid 2048 = 64 g-slots x 32 slices.
// w0/w1 reads use the TILED layout (contiguous permuted 1024B per wave read).
__global__ __launch_bounds__(256) __attribute__((amdgpu_waves_per_eu(2, 4)))
void rescore_kernel(
    const unsigned short* __restrict__ xgh, const unsigned short* __restrict__ xgl,
    const unsigned short* __restrict__ w0, const unsigned short* __restrict__ w1,
    const float* __restrict__ wnf, const int* __restrict__ ucount,
    float* __restrict__ p2v, int* __restrict__ p2c) {
  const int uc = *ucount;
  if (uc == 0) return;
  const int ucp = (uc + 63) & ~63;
  const int sl = blockIdx.x & 31, g0 = blockIdx.x >> 5;
  __shared__ float red2[4096];  // 16 KB: rv[2048] rc[2048]
  const int tid = threadIdx.x;
  const int lane = tid & 63, wv = tid >> 6;
  const int wm = wv & 1, wnb = wv >> 1;
  const int l15 = lane & 15, quad = lane >> 4;

  for (int g = g0; g * 64 < ucp; g += 64) {
    short8 ah[2][8], al[2][8];  // 128 VGPRs
#pragma unroll
    for (int mt = 0; mt < 2; ++mt) {
      const size_t rb = (size_t)(g * 64 + wm * 32 + mt * 16 + l15) * DIM + quad * 8;
#pragma unroll
      for (int kc = 0; kc < 8; ++kc) {
        ah[mt][kc] = *(const short8*)(xgh + rb + kc * 32);
        al[mt][kc] = *(const short8*)(xgl + rb + kc * 32);
      }
    }
    float bv[8];
    int bc[8];
#pragma unroll
    for (int i = 0; i < 8; ++i) { bv[i] = -3.4e38f; bc[i] = 0; }

    // tiled base: rows sl*256 + wnb*32 -> tile sl*8 + wnb; +2 tiles per sub
    const unsigned short* wtb0 = w0 + (size_t)(sl * 8 + wnb) * 8192;
    const unsigned short* wtb1 = w1 + (size_t)(sl * 8 + wnb) * 8192;
    const float* wnp = wnf + sl * 256 + wnb * 32 + l15;
    int code0 = sl * 256 + wnb * 32 + l15;

#pragma unroll 1
    for (int sub = 0; sub < 4; ++sub) {
      floatx4 acc[2][2];
#pragma unroll
      for (int mt = 0; mt < 2; ++mt)
#pragma unroll
        for (int nt = 0; nt < 2; ++nt) acc[mt][nt] = (floatx4){0.f, 0.f, 0.f, 0.f};
#pragma unroll
      for (int kc = 0; kc < 8; ++kc) {
        const int so = kc * 1024 + (quad * 16 + (l15 ^ kc)) * 8;  // region kc*2+h, slot
        const short8 bh0 = *(const short8*)(wtb0 + so);
        const short8 bh1 = *(const short8*)(wtb0 + so + 512);
        const short8 bl0 = *(const short8*)(wtb1 + so);
        const short8 bl1 = *(const short8*)(wtb1 + so + 512);
#pragma unroll
        for (int mt = 0; mt < 2; ++mt) {
          acc[mt][0] = __builtin_amdgcn_mfma_f32_16x16x32_bf16(al[mt][kc], bl0, acc[mt][0], 0, 0, 0);
          acc[mt][0] = __builtin_amdgcn_mfma_f32_16x16x32_bf16(ah[mt][kc], bl0, acc[mt][0], 0, 0, 0);
          acc[mt][0] = __builtin_amdgcn_mfma_f32_16x16x32_bf16(al[mt][kc], bh0, acc[mt][0], 0, 0, 0);
          acc[mt][0] = __builtin_amdgcn_mfma_f32_16x16x32_bf16(ah[mt][kc], bh0, acc[mt][0], 0, 0, 0);
          acc[mt][1] = __builtin_amdgcn_mfma_f32_16x16x32_bf16(al[mt][kc], bl1, acc[mt][1], 0, 0, 0);
          acc[mt][1] = __builtin_amdgcn_mfma_f32_16x16x32_bf16(ah[mt][kc], bl1, acc[mt][1], 0, 0, 0);
          acc[mt][1] = __builtin_amdgcn_mfma_f32_16x16x32_bf16(al[mt][kc], bh1, acc[mt][1], 0, 0, 0);
          acc[mt][1] = __builtin_amdgcn_mfma_f32_16x16x32_bf16(ah[mt][kc], bh1, acc[mt][1], 0, 0, 0);
        }
      }
      const float wn0 = wnp[0], wn1 = wnp[16];
      // acc = -(x.w); dist = wn + 2*acc
#pragma unroll
      for (int mt = 0; mt < 2; ++mt) {
#pragma unroll
        for (int reg = 0; reg < 4; ++reg) {
          const int cell = mt * 4 + reg;
          const float d0 = fmaf(2.0f, acc[mt][0][reg], wn0);
          const float d1 = fmaf(2.0f, acc[mt][1][reg], wn1);
          const float hi = fmaxf(d0, d1);
          const int ch = (d1 > d0) ? (code0 + 16) : code0;  // tie -> lower code
          bc[cell] = (hi > bv[cell]) ? ch : bc[cell];
          bv[cell] = fmaxf(bv[cell], hi);
        }
      }
      wtb0 += 16384;   // 2 tiles (64 rows)
      wtb1 += 16384;
      wnp += 64;
      code0 += 64;
    }

    // epilogue: cross-column reduce for this g-group
    float* rv = red2;
    int* rc = (int*)(red2 + 2048);
    __syncthreads();  // protect red2 reuse across g iterations
    const int cg = wnb * 16 + l15;
#pragma unroll
    for (int mt = 0; mt < 2; ++mt)
#pragma unroll
      for (int reg = 0; reg < 4; ++reg) {
        const int tok = wm * 32 + mt * 16 + quad * 4 + reg;
        rv[tok * 32 + cg] = bv[mt * 4 + reg];
        rc[tok * 32 + cg] = bc[mt * 4 + reg];
      }
    __syncthreads();
    if (tid < 64) {
      const int s = g * 64 + tid;
      if (s < uc) {
        float V = rv[tid * 32];
        int C = rc[tid * 32];
#pragma unroll 4
        for (int j = 1; j < 32; ++j) {
          const float v = rv[tid * 32 + j];
          const int c = rc[tid * 32 + j];
          if (v > V || (v == V && c < C)) { V = v; C = c; }
        }
        p2v[(size_t)sl * NTOK + s] = V;
        p2c[(size_t)sl * NTOK + s] = C;
      }
    }
  }
}

// ---- kernel 6: fused slice-merge + gather ----
__global__ __launch_bounds__(256) void gather_kernel(const float* __restrict__ w,
    const int* __restrict__ final_idx, const float* __restrict__ p2v,
    const int* __restrict__ p2c, float* __restrict__ out) {
  const int lane = threadIdx.x & 63;
  const int n = blockIdx.x * 4 + (threadIdx.x >> 6);
  int f = final_idx[n];
  if (f & UFLAG) {
    const int s = f & 0x3FFF;
    const int sl = lane & 31;
    float v = p2v[(size_t)sl * NTOK + s];
    int c = p2c[(size_t)sl * NTOK + s];
#pragma unroll
    for (int off = 1; off < 32; off <<= 1) {
      const float ov = __shfl_xor(v, off);
      const int oc = __shfl_xor(c, off);
      if (ov > v || (ov == v && oc < c)) { v = ov; c = oc; }
    }
    f = c;  // uniform across each 32-lane half (both halves identical)
  }
  ((float4*)(out + (size_t)n * DIM))[lane] = ((const float4*)(w + (size_t)f * DIM))[lane];
}

extern "C" void kernel_launch(void* const* d_in, const int* in_sizes, int n_in,
                              void* d_out, int out_size, void* d_ws, size_t ws_size,
                              hipStream_t stream) {
  const float* x = (const float*)d_in[0];
  const float* w = (const float*)d_in[1];
  float* out = (float*)d_out;

  char* ws = (char*)d_ws;   // ~39.5 MB used
  unsigned short* x0n = (unsigned short*)(ws);             // 8388608
  unsigned short* w0 = (unsigned short*)(ws + 8388608);    // 4194304 (tiled)
  unsigned short* w1 = (unsigned short*)(ws + 12582912);   // 4194304 (tiled)
  float* wn2 = (float*)(ws + 16777216);                    // 32768
  float* wnf = (float*)(ws + 16809984);                    // 32768
  float* pv1 = (float*)(ws + 16842752);                    // 524288
  int*   pc1 = (int*)  (ws + 17367040);                    // 524288
  float* pv2 = (float*)(ws + 17891328);                    // 524288
  int* final_idx = (int*)(ws + 18415616);                  // 65536
  int* ucount = (int*)(ws + 18481152);                     // 256
  int* ulist  = (int*)(ws + 18481408);                     // 65536
  unsigned short* xgh = (unsigned short*)(ws + 18546944);  // 8388608
  unsigned short* xgl = (unsigned short*)(ws + 26935552);  // 8388608
  float* p2v = (float*)(ws + 35324160);                    // 2097152
  int*   p2c = (int*)  (ws + 37421312);                    // 2097152

  prep_kernel<<<3072, 256, 0, stream>>>(x, w, x0n, w0, w1, wn2, wnf, ucount);
  phase1_kernel<<<128 * NCBG, 256, 0, stream>>>(x0n, w0, wn2, pv1, pc1, pv2);
  reduce_kernel<<<NTOK / 256, 256, 0, stream>>>(pv1, pc1, pv2, final_idx, ucount, ulist);
  xgather_kernel<<<256, 256, 0, stream>>>(x, x0n, ucount, ulist, xgh, xgl);
  rescore_kernel<<<64 * 32, 256, 0, stream>>>(xgh, xgl, w0, w1, wnf, ucount, p2v, p2c);
  gather_kernel<<<NTOK / 4, 256, 0, stream>>>(w, final_idx, p2v, p2c, out);
}

// Round 8
// 192.963 us; speedup vs baseline: 1.3046x; 1.0070x over previous
//
#include <hip/hip_runtime.h>
#include <cstddef>
#include <cstdint>

#define DIM   256
#define KCODE 8192
#define NTOK  16384
#define NCBG  8          // phase1 code groups of 1024
#define HMARGIN 0.25f    // phase1 works in half-units (0.5*wn - dot)
#define UFLAG 0x40000000

typedef __attribute__((ext_vector_type(8))) short short8;
typedef __attribute__((ext_vector_type(8))) unsigned short ushort8;
typedef __attribute__((ext_vector_type(4))) unsigned short ushort4v;
typedef __attribute__((ext_vector_type(4))) float floatx4;

__device__ __forceinline__ unsigned short f2bf(float f) {  // RNE float->bf16
  uint32_t u = __builtin_bit_cast(uint32_t, f);
  return (unsigned short)((u + 0x7fffu + ((u >> 16) & 1u)) >> 16);
}
__device__ __forceinline__ float bf2f(unsigned short h) {
  return __builtin_bit_cast(float, (uint32_t)h << 16);
}

typedef const __attribute__((address_space(1))) unsigned int guint_t;
typedef __attribute__((address_space(3))) unsigned int luint_t;
__device__ __forceinline__ void gload_lds16(const void* g, void* l) {
  __builtin_amdgcn_global_load_lds((guint_t*)g, (luint_t*)l, 16, 0, 0);
}

// ---- TILED w0/w1 global layout (verified bit-exact since R3) ----
// tile t = 32 codebook rows (16 KB). Region (kc,h) = 1024 B at (kc*2+h)*1024.
// Slot s = quad*16 + (l15^kc) (16 B) holds chunk (row h*16+l15, 16B-col kc*4+quad).
// A wave DMA of one region (base + lane*16) is contiguous 1024 B in global AND
// lands as the conflict-free k-major LDS image (reads: lane*16 ^ kc<<4).

// ---- kernel 1: bf16 split convert (x negated, w two-word TILED) + w norms ----
__global__ __launch_bounds__(256) void prep_kernel(const float* __restrict__ x,
    const float* __restrict__ w, unsigned short* __restrict__ x0n,
    unsigned short* __restrict__ w0, unsigned short* __restrict__ w1,
    float* __restrict__ wn2, float* __restrict__ wnf, int* __restrict__ ucount) {
  if (blockIdx.x == 0 && threadIdx.x == 0) *ucount = 0;
  const int lane = threadIdx.x & 63, wv = threadIdx.x >> 6;
  const int l32 = lane & 31;
  const int row = blockIdx.x * 8 + wv * 2 + (lane >> 5);
  const bool is_x = row < NTOK;
  const float* src = is_x ? (x + (size_t)row * DIM) : (w + (size_t)(row - NTOK) * DIM);
  const float4 f0 = ((const float4*)src)[l32 * 2];
  const float4 f1 = ((const float4*)src)[l32 * 2 + 1];
  const float f[8] = {f0.x, f0.y, f0.z, f0.w, f1.x, f1.y, f1.z, f1.w};
  if (is_x) {  // store bf16(-x): MFMA then accumulates (norm - dot) directly
    ushort8 o;
#pragma unroll
    for (int i = 0; i < 8; ++i) o[i] = f2bf(-f[i]);
    *(ushort8*)(x0n + (size_t)row * DIM + l32 * 8) = o;
  } else {     // two-word split: w = w0 + w1 (+ ~2^-17 residual), TILED store
    ushort8 h8, l8;
#pragma unroll
    for (int i = 0; i < 8; ++i) {
      h8[i] = f2bf(f[i]);
      l8[i] = f2bf(f[i] - bf2f(h8[i]));
    }
    const int wr = row - NTOK;
    const int kc = l32 >> 2, quad = l32 & 3;
    const size_t off = (size_t)(wr >> 5) * 8192                      // tile (shorts)
                     + (size_t)(kc * 2 + ((wr >> 4) & 1)) * 512      // region
                     + (size_t)(quad * 16 + ((wr & 15) ^ kc)) * 8;   // slot
    *(ushort8*)(w0 + off) = h8;
    *(ushort8*)(w1 + off) = l8;
    float s = f[0]*f[0] + f[1]*f[1] + f[2]*f[2] + f[3]*f[3] +
              f[4]*f[4] + f[5]*f[5] + f[6]*f[6] + f[7]*f[7];
#pragma unroll
    for (int off2 = 1; off2 < 32; off2 <<= 1) s += __shfl_xor(s, off2);
    if (l32 == 0) { wn2[wr] = 0.5f * s; wnf[wr] = s; }
  }
}

// ---- kernel 2: phase1 bf16 screen. 32 tok/wave; B via DMA ring-3. ----
// T3+T4 on the R7 base: ring of 3 x 16KB tiles, prefetch distance 2, per sub:
// s_waitcnt vmcnt(6) [FIFO: tile s(4) + tile s+1(4) + wn prefetch(2) = 10
// outstanding -> wait leaves 6 -> tile s landed], raw s_barrier, fence, issue
// tile s+2 into buf (s-1)%3 (all waves passed compute(s-1) at the barrier ->
// race-free), compute tile s. DMA gets TWO compute phases (~800cyc) to land
// and the queue is never drained (R7's __syncthreads drained vmcnt(0) per
// sub = the residual stall). Small reg footprint (R7: VGPR=80) so the R2-R4
// spill trap doesn't apply; WRITE_SIZE is the spill canary.
__global__ __launch_bounds__(256) __attribute__((amdgpu_waves_per_eu(3, 8)))
void phase1_kernel(
    const unsigned short* __restrict__ x0n, const unsigned short* __restrict__ w0,
    const float* __restrict__ wn2,
    float* __restrict__ pv1, int* __restrict__ pc1, float* __restrict__ pv2) {
  __shared__ char smem[49152];  // ring 3 x 16KB
  const int tid = threadIdx.x;
  const int tb = blockIdx.x >> 3;    // 0..127 (128 tokens)
  const int cbg = blockIdx.x & 7;    // blockIdx%8 = XCD -> 512KB w0 slice per XCD L2
  const int lane = tid & 63, wv = tid >> 6;
  const int l15 = lane & 15, quad = lane >> 4;
  const int lane16 = lane << 4;

  // resident A FIRST in vmcnt FIFO: wave wv owns 32 tokens; af[2][8] = 64 VGPRs
  short8 af[2][8];
#pragma unroll
  for (int mt = 0; mt < 2; ++mt) {
    const unsigned short* xr =
        x0n + (size_t)(tb * 128 + wv * 32 + mt * 16 + l15) * DIM + quad * 8;
#pragma unroll
    for (int kc = 0; kc < 8; ++kc) af[mt][kc] = *(const short8*)(xr + kc * 32);
  }

  // DMA sources: wave wv stages regions rho = wv*4+j; contiguous 1024B each.
  const char* wb = (const char*)w0 + (size_t)cbg * 32 * 16384;  // 512KB slice
  const char* g0 = wb + (wv * 4 + 0) * 1024 + lane16;
  const char* g1 = wb + (wv * 4 + 1) * 1024 + lane16;
  const char* g2 = wb + (wv * 4 + 2) * 1024 + lane16;
  const char* g3 = wb + (wv * 4 + 3) * 1024 + lane16;

  float bv1[8], bv2[8];
  int bc1[8];
#pragma unroll
  for (int i = 0; i < 8; ++i) { bv1[i] = -3.4e38f; bv2[i] = -3.4e38f; bc1[i] = 0; }

#define P1_DMA(BUFOFF) { \
    gload_lds16(g0, smem + (BUFOFF) + (wv * 4 + 0) * 1024); \
    gload_lds16(g1, smem + (BUFOFF) + (wv * 4 + 1) * 1024); \
    gload_lds16(g2, smem + (BUFOFF) + (wv * 4 + 2) * 1024); \
    gload_lds16(g3, smem + (BUFOFF) + (wv * 4 + 3) * 1024); \
    g0 += 16384; g1 += 16384; g2 += 16384; g3 += 16384; }

// counted wait: tile s landed; barrier: all waves' portions landed AND all
// waves are past compute(s-1); fence: nothing sinks/hoists across.
#define P1_WAIT(N) \
    asm volatile("s_waitcnt vmcnt(" #N ")" ::: "memory"); \
    __builtin_amdgcn_s_barrier(); \
    asm volatile("" ::: "memory");

#define P1_COMPUTE(BUF, LOADN) { \
    const float cw0 = nw0, cw1 = nw1; \
    wnp += 32; \
    if (LOADN) { nw0 = wnp[0]; nw1 = wnp[16]; } \
    floatx4 acc[2][2]; \
    _Pragma("unroll") \
    for (int mt = 0; mt < 2; ++mt) { \
      acc[mt][0] = (floatx4){cw0, cw0, cw0, cw0}; \
      acc[mt][1] = (floatx4){cw1, cw1, cw1, cw1}; \
    } \
    _Pragma("unroll") \
    for (int kc = 0; kc < 8; ++kc) { \
      const int ra = lane16 ^ (kc << 4); \
      const short8 b0 = *(const short8*)(smem + (BUF) + kc * 2048 + ra); \
      const short8 b1 = *(const short8*)(smem + (BUF) + kc * 2048 + 1024 + ra); \
      _Pragma("unroll") \
      for (int mt = 0; mt < 2; ++mt) { \
        acc[mt][0] = __builtin_amdgcn_mfma_f32_16x16x32_bf16(af[mt][kc], b0, acc[mt][0], 0, 0, 0); \
        acc[mt][1] = __builtin_amdgcn_mfma_f32_16x16x32_bf16(af[mt][kc], b1, acc[mt][1], 0, 0, 0); \
      } \
    } \
    _Pragma("unroll") \
    for (int mt = 0; mt < 2; ++mt) { \
      _Pragma("unroll") \
      for (int reg = 0; reg < 4; ++reg) { \
        const int cell = mt * 4 + reg; \
        const float c0 = acc[mt][0][reg], c1 = acc[mt][1][reg]; \
        const float hi = fmaxf(c0, c1), lo = fminf(c0, c1); \
        const int ch = (c1 > c0) ? (code0 + 16) : code0;  /* tie -> lower code */ \
        const float t = fminf(bv1[cell], hi); \
        bc1[cell] = (hi > bv1[cell]) ? ch : bc1[cell];    /* tie -> earlier */ \
        bv1[cell] = fmaxf(bv1[cell], hi); \
        bv2[cell] = fmaxf(fmaxf(bv2[cell], t), lo);       /* v_max3_f32 */ \
      } \
    } \
    code0 += 32; }

  P1_DMA(0)       // tile 0 -> buf0
  P1_DMA(16384)   // tile 1 -> buf1
  const float* wnp = wn2 + cbg * 1024 + l15;
  float nw0 = wnp[0], nw1 = wnp[16];   // wn(0): 2 VMEM, newest in FIFO
  int code0 = cbg * 1024 + l15;

  // subs 0..29 (uniform: WAIT(6), issue tile s+2, compute s), 3-unrolled.
#pragma unroll 1
  for (int s3 = 0; s3 < 10; ++s3) {
    P1_WAIT(6) P1_DMA(32768) P1_COMPUTE(0, 1)       // s=3k:   buf0, issue->buf2
    P1_WAIT(6) P1_DMA(0)     P1_COMPUTE(16384, 1)   // s=3k+1: buf1, issue->buf0
    P1_WAIT(6) P1_DMA(16384) P1_COMPUTE(32768, 1)   // s=3k+2: buf2, issue->buf1
  }
  P1_WAIT(6) P1_COMPUTE(0, 1)       // s=30: buf0 (tile 30), prefetch wn(31)
  P1_WAIT(2) P1_COMPUTE(16384, 0)   // s=31: buf1 (tile 31); wn(31) is newest 2
#undef P1_DMA
#undef P1_WAIT
#undef P1_COMPUTE

  // epilogue: the 16 per-token candidates live in lanes quad*16+l15 of THIS
  // wave -> 16-lane xor-butterfly top-2 merge, no LDS, no barriers.
  // Ties: V2 ends == V1 -> gap 0 -> rescore; lane 0 keeps lowest tying code.
#pragma unroll
  for (int mt = 0; mt < 2; ++mt)
#pragma unroll
    for (int reg = 0; reg < 4; ++reg) {
      const int cell = mt * 4 + reg;
      float V1 = bv1[cell], V2 = bv2[cell];
      int C1 = bc1[cell];
#pragma unroll
      for (int off = 1; off < 16; off <<= 1) {
        const float ov1 = __shfl_xor(V1, off);
        const float ov2 = __shfl_xor(V2, off);
        const int   oc1 = __shfl_xor(C1, off);
        const bool take = ov1 > V1;
        V2 = fmaxf(fminf(V1, ov1), take ? ov2 : V2);
        V1 = take ? ov1 : V1;
        C1 = take ? oc1 : C1;
      }
      if (l15 == 0) {
        const int tok = wv * 32 + mt * 16 + quad * 4 + reg;  // C/D: row=quad*4+reg
        const size_t o = (size_t)cbg * NTOK + tb * 128 + tok;
        pv1[o] = V1; pc1[o] = C1; pv2[o] = V2;
      }
    }
}

// ---- kernel 3: merge 8 code-group partials; flagged final_idx + uncertain list ----
__global__ __launch_bounds__(256) void reduce_kernel(
    const float* __restrict__ pv1, const int* __restrict__ pc1,
    const float* __restrict__ pv2, int* __restrict__ final_idx,
    int* __restrict__ ucount, int* __restrict__ ulist) {
  const int n = blockIdx.x * 256 + threadIdx.x;
  float V1 = -3.4e38f, V2 = -3.4e38f;
  int C1 = 0;
#pragma unroll
  for (int cb = 0; cb < NCBG; ++cb) {
    const size_t o = (size_t)cb * NTOK + n;
    const float v1 = pv1[o], v2 = pv2[o];
    const int c1 = pc1[o];
    if (v1 > V1) { V2 = fmaxf(V1, v2); V1 = v1; C1 = c1; }
    else V2 = fmaxf(V2, v1);
  }
  if (V1 - V2 < HMARGIN) {
    const int p = atomicAdd(ucount, 1);
    ulist[p] = n;
    final_idx[n] = UFLAG | p;   // gather resolves via p2 slot p
  } else {
    final_idx[n] = C1;
  }
}

// ---- kernel 4: gather uncertain tokens into compact two-word bf16 rows ----
__global__ __launch_bounds__(256) void xgather_kernel(const float* __restrict__ x,
    const unsigned short* __restrict__ x0n, const int* __restrict__ ucount,
    const int* __restrict__ ulist, unsigned short* __restrict__ xgh,
    unsigned short* __restrict__ xgl) {
  const int uc = *ucount;
  const int ucp = (uc + 63) & ~63;
  const int wgid = blockIdx.x * 4 + (threadIdx.x >> 6);
  const int lane = threadIdx.x & 63;
  for (int s = wgid; s < ucp; s += 1024) {
    ushort4v h = (ushort4v){0, 0, 0, 0}, l = (ushort4v){0, 0, 0, 0};
    if (s < uc) {
      const int tok = ulist[s];
      h = ((const ushort4v*)(x0n + (size_t)tok * DIM))[lane];
      const float4 f = ((const float4*)(x + (size_t)tok * DIM))[lane];
      l[0] = f2bf(-f.x - bf2f(h[0]));
      l[1] = f2bf(-f.y - bf2f(h[1]));
      l[2] = f2bf(-f.z - bf2f(h[2]));
      l[3] = f2bf(-f.w - bf2f(h[3]));
    }
    ((ushort4v*)(xgh + (size_t)s * DIM))[lane] = h;
    ((ushort4v*)(xgl + (size_t)s * DIM))[lane] = l;
  }
}

// ---- kernel 5: exact-ish rescore via 2-word bf16 split MFMA (4 products) ----
// block = 64 slots x 256-code slice; grid 2048 = 64 g-slots x 32 slices.
// w0/w1 reads use the TILED layout (contiguous permuted 1024B per wave read).
__global__ __launch_bounds__(256) __attribute__((amdgpu_waves_per_eu(2, 4)))
void rescore_kernel(
    const unsigned short* __restrict__ xgh, const unsigned short* __restrict__ xgl,
    const unsigned short* __restrict__ w0, const unsigned short* __restrict__ w1,
    const float* __restrict__ wnf, const int* __restrict__ ucount,
    float* __restrict__ p2v, int* __restrict__ p2c) {
  const int uc = *ucount;
  if (uc == 0) return;
  const int ucp = (uc + 63) & ~63;
  const int sl = blockIdx.x & 31, g0 = blockIdx.x >> 5;
  __shared__ float red2[4096];  // 16 KB: rv[2048] rc[2048]
  const int tid = threadIdx.x;
  const int lane = tid & 63, wv = tid >> 6;
  const int wm = wv & 1, wnb = wv >> 1;
  const int l15 = lane & 15, quad = lane >> 4;

  for (int g = g0; g * 64 < ucp; g += 64) {
    short8 ah[2][8], al[2][8];  // 128 VGPRs
#pragma unroll
    for (int mt = 0; mt < 2; ++mt) {
      const size_t rb = (size_t)(g * 64 + wm * 32 + mt * 16 + l15) * DIM + quad * 8;
#pragma unroll
      for (int kc = 0; kc < 8; ++kc) {
        ah[mt][kc] = *(const short8*)(xgh + rb + kc * 32);
        al[mt][kc] = *(const short8*)(xgl + rb + kc * 32);
      }
    }
    float bv[8];
    int bc[8];
#pragma unroll
    for (int i = 0; i < 8; ++i) { bv[i] = -3.4e38f; bc[i] = 0; }

    // tiled base: rows sl*256 + wnb*32 -> tile sl*8 + wnb; +2 tiles per sub
    const unsigned short* wtb0 = w0 + (size_t)(sl * 8 + wnb) * 8192;
    const unsigned short* wtb1 = w1 + (size_t)(sl * 8 + wnb) * 8192;
    const float* wnp = wnf + sl * 256 + wnb * 32 + l15;
    int code0 = sl * 256 + wnb * 32 + l15;

#pragma unroll 1
    for (int sub = 0; sub < 4; ++sub) {
      floatx4 acc[2][2];
#pragma unroll
      for (int mt = 0; mt < 2; ++mt)
#pragma unroll
        for (int nt = 0; nt < 2; ++nt) acc[mt][nt] = (floatx4){0.f, 0.f, 0.f, 0.f};
#pragma unroll
      for (int kc = 0; kc < 8; ++kc) {
        const int so = kc * 1024 + (quad * 16 + (l15 ^ kc)) * 8;  // region kc*2+h, slot
        const short8 bh0 = *(const short8*)(wtb0 + so);
        const short8 bh1 = *(const short8*)(wtb0 + so + 512);
        const short8 bl0 = *(const short8*)(wtb1 + so);
        const short8 bl1 = *(const short8*)(wtb1 + so + 512);
#pragma unroll
        for (int mt = 0; mt < 2; ++mt) {
          acc[mt][0] = __builtin_amdgcn_mfma_f32_16x16x32_bf16(al[mt][kc], bl0, acc[mt][0], 0, 0, 0);
          acc[mt][0] = __builtin_amdgcn_mfma_f32_16x16x32_bf16(ah[mt][kc], bl0, acc[mt][0], 0, 0, 0);
          acc[mt][0] = __builtin_amdgcn_mfma_f32_16x16x32_bf16(al[mt][kc], bh0, acc[mt][0], 0, 0, 0);
          acc[mt][0] = __builtin_amdgcn_mfma_f32_16x16x32_bf16(ah[mt][kc], bh0, acc[mt][0], 0, 0, 0);
          acc[mt][1] = __builtin_amdgcn_mfma_f32_16x16x32_bf16(al[mt][kc], bl1, acc[mt][1], 0, 0, 0);
          acc[mt][1] = __builtin_amdgcn_mfma_f32_16x16x32_bf16(ah[mt][kc], bl1, acc[mt][1], 0, 0, 0);
          acc[mt][1] = __builtin_amdgcn_mfma_f32_16x16x32_bf16(al[mt][kc], bh1, acc[mt][1], 0, 0, 0);
          acc[mt][1] = __builtin_amdgcn_mfma_f32_16x16x32_bf16(ah[mt][kc], bh1, acc[mt][1], 0, 0, 0);
        }
      }
      const float wn0 = wnp[0], wn1 = wnp[16];
      // acc = -(x.w); dist = wn + 2*acc
#pragma unroll
      for (int mt = 0; mt < 2; ++mt) {
#pragma unroll
        for (int reg = 0; reg < 4; ++reg) {
          const int cell = mt * 4 + reg;
          const float d0 = fmaf(2.0f, acc[mt][0][reg], wn0);
          const float d1 = fmaf(2.0f, acc[mt][1][reg], wn1);
          const float hi = fmaxf(d0, d1);
          const int ch = (d1 > d0) ? (code0 + 16) : code0;  // tie -> lower code
          bc[cell] = (hi > bv[cell]) ? ch : bc[cell];
          bv[cell] = fmaxf(bv[cell], hi);
        }
      }
      wtb0 += 16384;   // 2 tiles (64 rows)
      wtb1 += 16384;
      wnp += 64;
      code0 += 64;
    }

    // epilogue: cross-column reduce for this g-group
    float* rv = red2;
    int* rc = (int*)(red2 + 2048);
    __syncthreads();  // protect red2 reuse across g iterations
    const int cg = wnb * 16 + l15;
#pragma unroll
    for (int mt = 0; mt < 2; ++mt)
#pragma unroll
      for (int reg = 0; reg < 4; ++reg) {
        const int tok = wm * 32 + mt * 16 + quad * 4 + reg;
        rv[tok * 32 + cg] = bv[mt * 4 + reg];
        rc[tok * 32 + cg] = bc[mt * 4 + reg];
      }
    __syncthreads();
    if (tid < 64) {
      const int s = g * 64 + tid;
      if (s < uc) {
        float V = rv[tid * 32];
        int C = rc[tid * 32];
#pragma unroll 4
        for (int j = 1; j < 32; ++j) {
          const float v = rv[tid * 32 + j];
          const int c = rc[tid * 32 + j];
          if (v > V || (v == V && c < C)) { V = v; C = c; }
        }
        p2v[(size_t)sl * NTOK + s] = V;
        p2c[(size_t)sl * NTOK + s] = C;
      }
    }
  }
}

// ---- kernel 6: fused slice-merge + gather ----
__global__ __launch_bounds__(256) void gather_kernel(const float* __restrict__ w,
    const int* __restrict__ final_idx, const float* __restrict__ p2v,
    const int* __restrict__ p2c, float* __restrict__ out) {
  const int lane = threadIdx.x & 63;
  const int n = blockIdx.x * 4 + (threadIdx.x >> 6);
  int f = final_idx[n];
  if (f & UFLAG) {
    const int s = f & 0x3FFF;
    const int sl = lane & 31;
    float v = p2v[(size_t)sl * NTOK + s];
    int c = p2c[(size_t)sl * NTOK + s];
#pragma unroll
    for (int off = 1; off < 32; off <<= 1) {
      const float ov = __shfl_xor(v, off);
      const int oc = __shfl_xor(c, off);
      if (ov > v || (ov == v && oc < c)) { v = ov; c = oc; }
    }
    f = c;  // uniform across each 32-lane half (both halves identical)
  }
  ((float4*)(out + (size_t)n * DIM))[lane] = ((const float4*)(w + (size_t)f * DIM))[lane];
}

extern "C" void kernel_launch(void* const* d_in, const int* in_sizes, int n_in,
                              void* d_out, int out_size, void* d_ws, size_t ws_size,
                              hipStream_t stream) {
  const float* x = (const float*)d_in[0];
  const float* w = (const float*)d_in[1];
  float* out = (float*)d_out;

  char* ws = (char*)d_ws;   // ~39.5 MB used
  unsigned short* x0n = (unsigned short*)(ws);             // 8388608
  unsigned short* w0 = (unsigned short*)(ws + 8388608);    // 4194304 (tiled)
  unsigned short* w1 = (unsigned short*)(ws + 12582912);   // 4194304 (tiled)
  float* wn2 = (float*)(ws + 16777216);                    // 32768
  float* wnf = (float*)(ws + 16809984);                    // 32768
  float* pv1 = (float*)(ws + 16842752);                    // 524288
  int*   pc1 = (int*)  (ws + 17367040);                    // 524288
  float* pv2 = (float*)(ws + 17891328);                    // 524288
  int* final_idx = (int*)(ws + 18415616);                  // 65536
  int* ucount = (int*)(ws + 18481152);                     // 256
  int* ulist  = (int*)(ws + 18481408);                     // 65536
  unsigned short* xgh = (unsigned short*)(ws + 18546944);  // 8388608
  unsigned short* xgl = (unsigned short*)(ws + 26935552);  // 8388608
  float* p2v = (float*)(ws + 35324160);                    // 2097152
  int*   p2c = (int*)  (ws + 37421312);                    // 2097152

  prep_kernel<<<3072, 256, 0, stream>>>(x, w, x0n, w0, w1, wn2, wnf, ucount);
  phase1_kernel<<<128 * NCBG, 256, 0, stream>>>(x0n, w0, wn2, pv1, pc1, pv2);
  reduce_kernel<<<NTOK / 256, 256, 0, stream>>>(pv1, pc1, pv2, final_idx, ucount, ulist);
  xgather_kernel<<<256, 256, 0, stream>>>(x, x0n, ucount, ulist, xgh, xgl);
  rescore_kernel<<<64 * 32, 256, 0, stream>>>(xgh, xgl, w0, w1, wnf, ucount, p2v, p2c);
  gather_kernel<<<NTOK / 4, 256, 0, stream>>>(w, final_idx, p2v, p2c, out);
}